// Round 7
// baseline (214.039 us; speedup 1.0000x reference)
//
#include <hip/hip_runtime.h>

using u16 = unsigned short;
using u32 = unsigned int;

typedef __bf16 bf16x8 __attribute__((ext_vector_type(8)));
typedef __bf16 bf16x2 __attribute__((ext_vector_type(2)));
typedef float f32x4 __attribute__((ext_vector_type(4)));

__device__ __forceinline__ u16 f2b(float x) {
  u32 u = __builtin_bit_cast(u32, x);
  u += 0x7fffu + ((u >> 16) & 1u);   // RNE
  return (u16)(u >> 16);
}

// pack two f32 -> bf16x2 (low = first)
__device__ __forceinline__ u32 pk2(float lo, float hi) {
  bf16x2 t;
  t[0] = (__bf16)lo;
  t[1] = (__bf16)hi;
  return __builtin_bit_cast(u32, t);
}

__device__ __forceinline__ void gload16(const u16* g, u16* l) {
  __builtin_amdgcn_global_load_lds(
      (const __attribute__((address_space(1))) void*)g,
      (__attribute__((address_space(3))) void*)l, 16, 0, 0);
}

#define SCALE_Q 0.1803368801111204f   // 0.125 * log2(e): softmax in base-2
#define DEFER_THR 8.0f                // T13: P bounded by 2^8, fine in bf16/f32

// ---------------- fp32 -> bf16 convert (8 elems/thread) ----------------
__global__ void cvt_bf16_k(const float* __restrict__ s, u16* __restrict__ d, int n8) {
  int i = blockIdx.x * blockDim.x + threadIdx.x;
  int stride = gridDim.x * blockDim.x;
  for (; i < n8; i += stride) {
    float4 a = ((const float4*)s)[2 * i];
    float4 b = ((const float4*)s)[2 * i + 1];
    uint4 o;
    o.x = (u32)f2b(a.x) | ((u32)f2b(a.y) << 16);
    o.y = (u32)f2b(a.z) | ((u32)f2b(a.w) << 16);
    o.z = (u32)f2b(b.x) | ((u32)f2b(b.y) << 16);
    o.w = (u32)f2b(b.z) | ((u32)f2b(b.w) << 16);
    ((uint4*)d)[i] = o;
  }
}

// ---------------- bf16 GEMM, C = A * B^T (+bias) ----------------
// BK=64, G21 swizzle (pre-swizzled global source, linear gload_lds dest).
// MODE 0 (BM=128): N=3072. Scatter epilogue writes q [bh][s][64] (pre-scaled),
//   and K/V directly in the attention LDS-image layout:
//   K: [bh][tile t][r][c] where physical row r holds logical key L(r) of the
//      tile and c = dd ^ ((r&7)<<3)  (XOR swizzle, 8-elem granules).
//   V: [bh][tile t][dd][c] (transposed) with c = sl ^ ((dd&7)<<3).
// MODE 1 (BM=64):  N=1024, write fp32 to outf.
template <int MODE, int BM>
__global__ __launch_bounds__(256) void gemm_bt(
    const u16* __restrict__ A, const u16* __restrict__ Bm,
    const float* __restrict__ bias,
    u16* __restrict__ q, u16* __restrict__ k, u16* __restrict__ v,
    float* __restrict__ outf) {
  constexpr int KD = 1024;
  constexpr int MR = BM / 32;              // row-frags per wave
  constexpr int CA = BM / 8;               // A staging chunks (1KB each)
  const int n0 = blockIdx.x * 128;
  const int m0 = blockIdx.y * BM;
  const int tid = threadIdx.x;
  const int wid = tid >> 6;
  const int lane = tid & 63;
  const int wr = wid >> 1, wc = wid & 1;   // 2x2 waves; wave tile (BM/2) x 64
  const int fr = lane & 15, fg = lane >> 4;
  const int srow = lane >> 3;              // row within 8-row chunk
  const int scol = ((lane & 7) ^ (srow & 7)) * 8;   // pre-swizzled source col

  __shared__ __align__(16) u16 As[BM * 64];
  __shared__ __align__(16) u16 Bs[128 * 64];

  f32x4 acc[MR][4] = {};

  for (int k0 = 0; k0 < KD; k0 += 64) {
#pragma unroll
    for (int i = 0; i < CA / 4; ++i) {
      const int chunk = wid * (CA / 4) + i;
      gload16(A + (size_t)(m0 + chunk * 8 + srow) * KD + k0 + scol, As + chunk * 512);
    }
#pragma unroll
    for (int i = 0; i < 4; ++i) {
      const int chunk = wid * 4 + i;
      gload16(Bm + (size_t)(n0 + chunk * 8 + srow) * KD + k0 + scol, Bs + chunk * 512);
    }
    __syncthreads();
#pragma unroll
    for (int ks = 0; ks < 2; ++ks) {
      bf16x8 af[MR], bfr[4];
#pragma unroll
      for (int r = 0; r < MR; ++r) {
        const int row = wr * (BM / 2) + r * 16 + fr;
        af[r] = *(const bf16x8*)(As + row * 64 + ((ks * 32 + fg * 8) ^ ((row & 7) * 8)));
      }
#pragma unroll
      for (int c = 0; c < 4; ++c) {
        const int row = wc * 64 + c * 16 + fr;
        bfr[c] = *(const bf16x8*)(Bs + row * 64 + ((ks * 32 + fg * 8) ^ ((row & 7) * 8)));
      }
#pragma unroll
      for (int r = 0; r < MR; ++r)
#pragma unroll
        for (int c = 0; c < 4; ++c)
          acc[r][c] = __builtin_amdgcn_mfma_f32_16x16x32_bf16(af[r], bfr[c], acc[r][c], 0, 0, 0);
    }
    __syncthreads();
  }

#pragma unroll
  for (int r = 0; r < MR; ++r) {
#pragma unroll
    for (int c = 0; c < 4; ++c) {
      const int gcol = n0 + wc * 64 + c * 16 + fr;
      const float bv = bias[gcol];
#pragma unroll
      for (int g = 0; g < 4; ++g) {
        const int grow = m0 + wr * (BM / 2) + r * 16 + fg * 4 + g;
        float val = acc[r][c][g] + bv;
        if (MODE == 0) {
          const int which = gcol >> 10;          // 0=q 1=k 2=v
          const int dcol = gcol & 1023;
          const int hh = dcol >> 6, dd = dcol & 63;
          const int bb = grow >> 11, ss = grow & 2047;
          const int bhk = (bb << 4) + hh;
          const int t = ss >> 6, sl = ss & 63;
          if (which == 0) {
            q[((size_t)bhk * 2048 + ss) * 64 + dd] = f2b(val * SCALE_Q);
          } else if (which == 1) {
            // physical row r_ = Linv(sl): L(r_) = sl
            const int r_ = (sl & 32) | (((sl >> 2) & 1) << 4) | (((sl >> 4) & 1) << 3) |
                           (((sl >> 3) & 1) << 2) | (sl & 3);
            k[((size_t)bhk * 32 + t) * 4096 + r_ * 64 + (dd ^ ((r_ & 7) << 3))] = f2b(val);
          } else {
            v[((size_t)bhk * 32 + t) * 4096 + dd * 64 + (sl ^ ((dd & 7) << 3))] = f2b(val);
          }
        } else {
          outf[(size_t)grow * 1024 + gcol] = val;
        }
      }
    }
  }
}

// ---------------- flash attention fwd: pre-layouted KV, pure gload_lds staging ----------------
// Q: [32 bh][2048][64] bf16 (pre-scaled). KG/VG: [32 bh][32 t][4096] bf16 tile
// images (see gemm_bt). AO: [4096][1024] bf16.
// S^T = mfma(K,Q): lane holds q = lane&15. O^T = mfma(Vt, Pt): col = q = lane&15
// again -> softmax state and epilogue fully lane-local.
__global__ __launch_bounds__(256) void attn_fwd(
    const u16* __restrict__ Q, const u16* __restrict__ KG,
    const u16* __restrict__ VG, u16* __restrict__ AO) {
  const int wg = blockIdx.x;                     // 512
  const int newid = (wg & 7) * 64 + (wg >> 3);   // XCD swizzle (bijective: 512%8==0)
  const int bh = newid >> 4;
  const int qt = newid & 15;
  const int b = bh >> 4, h = bh & 15;

  const int tid = threadIdx.x, wid = tid >> 6, lane = tid & 63;
  const int fr = lane & 15, fg = lane >> 4;
  const int q0 = qt * 128 + wid * 32;

  __shared__ __align__(16) u16 Ks[2][4096];      // 8KB per buffer
  __shared__ __align__(16) u16 Vs[2][4096];

  // Q fragments (already scaled)
  const size_t qbase = (size_t)bh * (2048 * 64);
  bf16x8 qf[2][2];
#pragma unroll
  for (int rf = 0; rf < 2; ++rf)
#pragma unroll
    for (int ks = 0; ks < 2; ++ks)
      qf[rf][ks] = *(const bf16x8*)(Q + qbase + (size_t)(q0 + rf * 16 + fr) * 64 + ks * 32 + fg * 8);

  f32x4 o[2][4] = {};                       // O^T: col=q=fr, row=d=4*fg+g
  float mrow[2] = {-3.0e38f, -3.0e38f};
  float lrow[2] = {0.f, 0.f};

  const u16* kg = KG + (size_t)bh * 131072 + tid * 8;   // per-thread 16B slice
  const u16* vg = VG + (size_t)bh * 131072 + tid * 8;

#define STAGE(t, bufi) do {                                        \
    const u16* ksrc = kg + (t) * 4096;                             \
    const u16* vsrc = vg + (t) * 4096;                             \
    u16* kdst = (u16*)Ks[bufi] + wid * 512;                        \
    u16* vdst = (u16*)Vs[bufi] + wid * 512;                        \
    gload16(ksrc, kdst); gload16(ksrc + 2048, kdst + 2048);        \
    gload16(vsrc, vdst); gload16(vsrc + 2048, vdst + 2048);        \
  } while (0)

  STAGE(0, 0);
  __syncthreads();                          // drains vmcnt -> tile 0 staged

  for (int t = 0; t < 32; ++t) {
    const int cur = t & 1;
    if (t + 1 < 32) STAGE(t + 1, cur ^ 1);  // async, lands before next barrier
    const u16* kb = (const u16*)Ks[cur];
    const u16* vb = (const u16*)Vs[cur];

    bf16x8 kf[4][2], vf[4][2];
#pragma unroll
    for (int c = 0; c < 4; ++c)
#pragma unroll
      for (int ks = 0; ks < 2; ++ks)
        kf[c][ks] = *(const bf16x8*)(kb + (c * 16 + fr) * 64 + ((ks * 32 + fg * 8) ^ ((fr & 7) * 8)));
#pragma unroll
    for (int d = 0; d < 4; ++d)
#pragma unroll
      for (int ks = 0; ks < 2; ++ks)
        vf[d][ks] = *(const bf16x8*)(vb + (d * 16 + fr) * 64 + ((ks * 32 + fg * 8) ^ ((fr & 7) * 8)));

#pragma unroll
    for (int rf = 0; rf < 2; ++rf) {
      f32x4 p[4];
      __builtin_amdgcn_s_setprio(1);
#pragma unroll
      for (int c = 0; c < 4; ++c) {
        f32x4 z = {};
        z = __builtin_amdgcn_mfma_f32_16x16x32_bf16(kf[c][0], qf[rf][0], z, 0, 0, 0);
        z = __builtin_amdgcn_mfma_f32_16x16x32_bf16(kf[c][1], qf[rf][1], z, 0, 0, 0);
        p[c] = z;
      }
      __builtin_amdgcn_s_setprio(0);
      // row max: vector tree + horizontal + fg-group reduce
      f32x4 m01 = __builtin_elementwise_max(p[0], p[1]);
      f32x4 m23 = __builtin_elementwise_max(p[2], p[3]);
      f32x4 m4 = __builtin_elementwise_max(m01, m23);
      float mx = fmaxf(fmaxf(m4[0], m4[1]), fmaxf(m4[2], m4[3]));
      mx = fmaxf(mx, __shfl_xor(mx, 16));
      mx = fmaxf(mx, __shfl_xor(mx, 32));

      const float mold = mrow[rf];
      const bool defer = __all(mx <= mold + DEFER_THR);   // T13: wave-uniform skip
      float mnew = mold;
      if (!defer) {
        mnew = fmaxf(mold, mx);
        const float corr = __builtin_amdgcn_exp2f(mold - mnew);
        mrow[rf] = mnew;
        lrow[rf] *= corr;
#pragma unroll
        for (int d = 0; d < 4; ++d) o[rf][d] *= corr;     // lane-local: col(q)=fr
      }
#pragma unroll
      for (int c = 0; c < 4; ++c)
#pragma unroll
        for (int g = 0; g < 4; ++g)
          p[c][g] = __builtin_amdgcn_exp2f(p[c][g] - mnew);
      f32x4 s4 = (p[0] + p[1]) + (p[2] + p[3]);
      float rs = (s4[0] + s4[1]) + (s4[2] + s4[3]);
      rs += __shfl_xor(rs, 16);
      rs += __shfl_xor(rs, 32);
      lrow[rf] += rs;

      // P -> bf16 B-frags (P^T operand); key permutation makes this pack-only
      bf16x8 pa[2];
#pragma unroll
      for (int ks = 0; ks < 2; ++ks) {
        u32 w0 = pk2(p[2 * ks][0], p[2 * ks][1]);
        u32 w1 = pk2(p[2 * ks][2], p[2 * ks][3]);
        u32 w2 = pk2(p[2 * ks + 1][0], p[2 * ks + 1][1]);
        u32 w3 = pk2(p[2 * ks + 1][2], p[2 * ks + 1][3]);
        uint4 packed = {w0, w1, w2, w3};
        pa[ks] = __builtin_bit_cast(bf16x8, packed);
      }
      // O^T += V^T * P^T
      __builtin_amdgcn_s_setprio(1);
#pragma unroll
      for (int d = 0; d < 4; ++d) {
        o[rf][d] = __builtin_amdgcn_mfma_f32_16x16x32_bf16(vf[d][0], pa[0], o[rf][d], 0, 0, 0);
        o[rf][d] = __builtin_amdgcn_mfma_f32_16x16x32_bf16(vf[d][1], pa[1], o[rf][d], 0, 0, 0);
      }
      __builtin_amdgcn_s_setprio(0);
    }
    __syncthreads();            // drains vmcnt (tile t+1 staged) + LDS reads done
  }

  // epilogue: lane-local 1/l, packed 8B stores
#pragma unroll
  for (int rf = 0; rf < 2; ++rf) {
    const float rinv = __builtin_amdgcn_rcpf(lrow[rf]);
    const size_t rowoff = (size_t)(b * 2048 + q0 + rf * 16 + fr) * 1024 + h * 64;
#pragma unroll
    for (int d = 0; d < 4; ++d) {
      uint2 st;
      st.x = pk2(o[rf][d][0] * rinv, o[rf][d][1] * rinv);
      st.y = pk2(o[rf][d][2] * rinv, o[rf][d][3] * rinv);
      *(uint2*)(AO + rowoff + d * 16 + fg * 4) = st;
    }
  }
#undef STAGE
}

// ---------------- launch ----------------
extern "C" void kernel_launch(void* const* d_in, const int* in_sizes, int n_in,
                              void* d_out, int out_size, void* d_ws, size_t ws_size,
                              hipStream_t stream) {
  (void)in_sizes; (void)n_in; (void)out_size; (void)ws_size;
  const float* x     = (const float*)d_in[0];
  const float* w_in  = (const float*)d_in[1];
  const float* b_in  = (const float*)d_in[2];
  const float* w_out = (const float*)d_in[3];
  const float* b_out = (const float*)d_in[4];

  u16* xb    = (u16*)d_ws;                       // [4096,1024]
  u16* winb  = xb    + (size_t)4096 * 1024;      // [3072,1024]
  u16* woutb = winb  + (size_t)3072 * 1024;      // [1024,1024]
  u16* qb    = woutb + (size_t)1024 * 1024;      // [32,2048,64]
  u16* kb    = qb    + (size_t)4194304;          // [32,32,4096] tile images
  u16* vb    = kb    + (size_t)4194304;          // [32,32,4096] tile images
  u16* aob   = vb    + (size_t)4194304;          // [4096,1024]

  cvt_bf16_k<<<2048, 256, 0, stream>>>(x, xb, 4096 * 1024 / 8);
  cvt_bf16_k<<<1536, 256, 0, stream>>>(w_in, winb, 3072 * 1024 / 8);
  cvt_bf16_k<<<512, 256, 0, stream>>>(w_out, woutb, 1024 * 1024 / 8);

  gemm_bt<0, 128><<<dim3(24, 32), 256, 0, stream>>>(xb, winb, b_in, qb, kb, vb, nullptr);
  attn_fwd<<<512, 256, 0, stream>>>(qb, kb, vb, aob);
  gemm_bt<1, 64><<<dim3(8, 64), 256, 0, stream>>>(aob, woutb, b_out, nullptr, nullptr, nullptr,
                                                  (float*)d_out);
}

// Round 8
// 213.608 us; speedup vs baseline: 1.0020x; 1.0020x over previous
//
#include <hip/hip_runtime.h>

using u16 = unsigned short;
using u32 = unsigned int;

typedef __bf16 bf16x8 __attribute__((ext_vector_type(8)));
typedef __bf16 bf16x2 __attribute__((ext_vector_type(2)));
typedef float f32x4 __attribute__((ext_vector_type(4)));

__device__ __forceinline__ u16 f2b(float x) {
  u32 u = __builtin_bit_cast(u32, x);
  u += 0x7fffu + ((u >> 16) & 1u);   // RNE
  return (u16)(u >> 16);
}

// pack two f32 -> bf16x2 (low = first)
__device__ __forceinline__ u32 pk2(float lo, float hi) {
  bf16x2 t;
  t[0] = (__bf16)lo;
  t[1] = (__bf16)hi;
  return __builtin_bit_cast(u32, t);
}

__device__ __forceinline__ void gload16(const u16* g, u16* l) {
  __builtin_amdgcn_global_load_lds(
      (const __attribute__((address_space(1))) void*)g,
      (__attribute__((address_space(3))) void*)l, 16, 0, 0);
}

#define SCALE_Q 0.1803368801111204f   // 0.125 * log2(e): softmax in base-2
#define DEFER_THR 8.0f                // T13: P bounded by 2^8, fine in bf16/f32

// ---------------- fused fp32 -> bf16 convert (x, w_in, w_out -> contiguous ws) ----
// ranges in 8-elem units: x [0,524288), w_in [524288,917504), w_out [917504,1048576)
// all range boundaries are multiples of 256 -> branch is block-uniform.
__global__ __launch_bounds__(256) void cvt_all_k(
    const float* __restrict__ x, const float* __restrict__ w_in,
    const float* __restrict__ w_out, u16* __restrict__ dst) {
  const int i = blockIdx.x * 256 + threadIdx.x;
  const float* s;
  int j;
  if (i < 524288) { s = x; j = i; }
  else if (i < 917504) { s = w_in; j = i - 524288; }
  else { s = w_out; j = i - 917504; }
  float4 a = ((const float4*)s)[2 * j];
  float4 b = ((const float4*)s)[2 * j + 1];
  uint4 o;
  o.x = (u32)f2b(a.x) | ((u32)f2b(a.y) << 16);
  o.y = (u32)f2b(a.z) | ((u32)f2b(a.w) << 16);
  o.z = (u32)f2b(b.x) | ((u32)f2b(b.y) << 16);
  o.w = (u32)f2b(b.z) | ((u32)f2b(b.w) << 16);
  ((uint4*)dst)[i] = o;
}

// ---------------- bf16 GEMM, C = A * B^T (+bias) ----------------
// BK=64, G21 swizzle (pre-swizzled global source, linear gload_lds dest).
// MODE 0 (BM=128): N=3072. Scatter epilogue writes q [bh][s][64] (pre-scaled),
//   and K/V directly in the attention LDS-image layout:
//   K: [bh][tile t][r][c], physical row r holds logical key L(r) of the tile,
//      c = dd ^ ((r&7)<<3)  (XOR swizzle, 8-elem granules).
//   V: [bh][tile t][dd][c] (transposed), c = sl ^ ((dd&7)<<3).
// MODE 1 (BM=64):  N=1024, write fp32 to outf.
template <int MODE, int BM>
__global__ __launch_bounds__(256) void gemm_bt(
    const u16* __restrict__ A, const u16* __restrict__ Bm,
    const float* __restrict__ bias,
    u16* __restrict__ q, u16* __restrict__ k, u16* __restrict__ v,
    float* __restrict__ outf) {
  constexpr int KD = 1024;
  constexpr int MR = BM / 32;              // row-frags per wave
  constexpr int CA = BM / 8;               // A staging chunks (1KB each)
  const int n0 = blockIdx.x * 128;
  const int m0 = blockIdx.y * BM;
  const int tid = threadIdx.x;
  const int wid = tid >> 6;
  const int lane = tid & 63;
  const int wr = wid >> 1, wc = wid & 1;   // 2x2 waves; wave tile (BM/2) x 64
  const int fr = lane & 15, fg = lane >> 4;
  const int srow = lane >> 3;              // row within 8-row chunk
  const int scol = ((lane & 7) ^ (srow & 7)) * 8;   // pre-swizzled source col

  __shared__ __align__(16) u16 As[BM * 64];
  __shared__ __align__(16) u16 Bs[128 * 64];

  f32x4 acc[MR][4] = {};

  for (int k0 = 0; k0 < KD; k0 += 64) {
#pragma unroll
    for (int i = 0; i < CA / 4; ++i) {
      const int chunk = wid * (CA / 4) + i;
      gload16(A + (size_t)(m0 + chunk * 8 + srow) * KD + k0 + scol, As + chunk * 512);
    }
#pragma unroll
    for (int i = 0; i < 4; ++i) {
      const int chunk = wid * 4 + i;
      gload16(Bm + (size_t)(n0 + chunk * 8 + srow) * KD + k0 + scol, Bs + chunk * 512);
    }
    __syncthreads();
#pragma unroll
    for (int ks = 0; ks < 2; ++ks) {
      bf16x8 af[MR], bfr[4];
#pragma unroll
      for (int r = 0; r < MR; ++r) {
        const int row = wr * (BM / 2) + r * 16 + fr;
        af[r] = *(const bf16x8*)(As + row * 64 + ((ks * 32 + fg * 8) ^ ((row & 7) * 8)));
      }
#pragma unroll
      for (int c = 0; c < 4; ++c) {
        const int row = wc * 64 + c * 16 + fr;
        bfr[c] = *(const bf16x8*)(Bs + row * 64 + ((ks * 32 + fg * 8) ^ ((row & 7) * 8)));
      }
#pragma unroll
      for (int r = 0; r < MR; ++r)
#pragma unroll
        for (int c = 0; c < 4; ++c)
          acc[r][c] = __builtin_amdgcn_mfma_f32_16x16x32_bf16(af[r], bfr[c], acc[r][c], 0, 0, 0);
    }
    __syncthreads();
  }

#pragma unroll
  for (int r = 0; r < MR; ++r) {
#pragma unroll
    for (int c = 0; c < 4; ++c) {
      const int gcol = n0 + wc * 64 + c * 16 + fr;
      const float bv = bias[gcol];
#pragma unroll
      for (int g = 0; g < 4; ++g) {
        const int grow = m0 + wr * (BM / 2) + r * 16 + fg * 4 + g;
        float val = acc[r][c][g] + bv;
        if (MODE == 0) {
          const int which = gcol >> 10;          // 0=q 1=k 2=v
          const int dcol = gcol & 1023;
          const int hh = dcol >> 6, dd = dcol & 63;
          const int bb = grow >> 11, ss = grow & 2047;
          const int bhk = (bb << 4) + hh;
          const int t = ss >> 6, sl = ss & 63;
          if (which == 0) {
            q[((size_t)bhk * 2048 + ss) * 64 + dd] = f2b(val * SCALE_Q);
          } else if (which == 1) {
            // physical row r_ = Linv(sl): L(r_) = sl
            const int r_ = (sl & 32) | (((sl >> 2) & 1) << 4) | (((sl >> 4) & 1) << 3) |
                           (((sl >> 3) & 1) << 2) | (sl & 3);
            k[((size_t)bhk * 32 + t) * 4096 + r_ * 64 + (dd ^ ((r_ & 7) << 3))] = f2b(val);
          } else {
            v[((size_t)bhk * 32 + t) * 4096 + dd * 64 + (sl ^ ((dd & 7) << 3))] = f2b(val);
          }
        } else {
          outf[(size_t)grow * 1024 + gcol] = val;
        }
      }
    }
  }
}

// ---------------- flash attention fwd: pre-layouted KV, QBLK=64, 4 blocks/CU ----------------
// Q: [32 bh][2048][64] bf16 (pre-scaled). KG/VG: [32 bh][32 t][4096] bf16 tile
// images (see gemm_bt). AO: [4096][1024] bf16.
// 1024 blocks of 4 waves x 16 q-rows: 4 blocks/CU -> latency hiding across
// blocks (R6/R7 lesson: 2 blocks/CU left both pipes idle ~35% of cycles).
// S^T = mfma(K,Q): lane holds q = lane&15. O^T = mfma(Vt, Pt): col = q = lane&15
// again -> softmax state and epilogue fully lane-local.
__global__ __launch_bounds__(256) void attn_fwd(
    const u16* __restrict__ Q, const u16* __restrict__ KG,
    const u16* __restrict__ VG, u16* __restrict__ AO) {
  const int wg = blockIdx.x;                      // 1024
  const int newid = (wg & 7) * 128 + (wg >> 3);   // XCD swizzle (bijective: 1024%8==0)
  const int bh = newid >> 5;                      // 4 heads per XCD -> KV L2-hot
  const int qt = newid & 31;
  const int b = bh >> 4, h = bh & 15;

  const int tid = threadIdx.x, wid = tid >> 6, lane = tid & 63;
  const int fr = lane & 15, fg = lane >> 4;
  const int q0 = qt * 64 + wid * 16;

  __shared__ __align__(16) u16 Ks[2][4096];       // 8KB per buffer
  __shared__ __align__(16) u16 Vs[2][4096];

  // Q fragments (already scaled)
  const size_t qbase = (size_t)bh * (2048 * 64);
  bf16x8 qf[2];
#pragma unroll
  for (int ks = 0; ks < 2; ++ks)
    qf[ks] = *(const bf16x8*)(Q + qbase + (size_t)(q0 + fr) * 64 + ks * 32 + fg * 8);

  f32x4 o[4] = {};                          // O^T: col=q=fr, row=d=4*fg+g
  float mrow = -3.0e38f;
  float lrow = 0.f;

  const u16* kg = KG + (size_t)bh * 131072 + tid * 8;   // per-thread 16B slice
  const u16* vg = VG + (size_t)bh * 131072 + tid * 8;

#define STAGE(t, bufi) do {                                        \
    const u16* ksrc = kg + (t) * 4096;                             \
    const u16* vsrc = vg + (t) * 4096;                             \
    u16* kdst = (u16*)Ks[bufi] + wid * 512;                        \
    u16* vdst = (u16*)Vs[bufi] + wid * 512;                        \
    gload16(ksrc, kdst); gload16(ksrc + 2048, kdst + 2048);        \
    gload16(vsrc, vdst); gload16(vsrc + 2048, vdst + 2048);        \
  } while (0)

  STAGE(0, 0);
  __syncthreads();                          // drains vmcnt -> tile 0 staged

  for (int t = 0; t < 32; ++t) {
    const int cur = t & 1;
    if (t + 1 < 32) STAGE(t + 1, cur ^ 1);  // async, lands before next barrier
    const u16* kb = (const u16*)Ks[cur];
    const u16* vb = (const u16*)Vs[cur];

    bf16x8 kf[4][2], vf[4][2];
#pragma unroll
    for (int c = 0; c < 4; ++c)
#pragma unroll
      for (int ks = 0; ks < 2; ++ks)
        kf[c][ks] = *(const bf16x8*)(kb + (c * 16 + fr) * 64 + ((ks * 32 + fg * 8) ^ ((fr & 7) * 8)));
#pragma unroll
    for (int d = 0; d < 4; ++d)
#pragma unroll
      for (int ks = 0; ks < 2; ++ks)
        vf[d][ks] = *(const bf16x8*)(vb + (d * 16 + fr) * 64 + ((ks * 32 + fg * 8) ^ ((fr & 7) * 8)));

    f32x4 p[4];
    __builtin_amdgcn_s_setprio(1);
#pragma unroll
    for (int c = 0; c < 4; ++c) {
      f32x4 z = {};
      z = __builtin_amdgcn_mfma_f32_16x16x32_bf16(kf[c][0], qf[0], z, 0, 0, 0);
      z = __builtin_amdgcn_mfma_f32_16x16x32_bf16(kf[c][1], qf[1], z, 0, 0, 0);
      p[c] = z;
    }
    __builtin_amdgcn_s_setprio(0);
    // row max: vector tree + horizontal + fg-group reduce
    f32x4 m01 = __builtin_elementwise_max(p[0], p[1]);
    f32x4 m23 = __builtin_elementwise_max(p[2], p[3]);
    f32x4 m4 = __builtin_elementwise_max(m01, m23);
    float mx = fmaxf(fmaxf(m4[0], m4[1]), fmaxf(m4[2], m4[3]));
    mx = fmaxf(mx, __shfl_xor(mx, 16));
    mx = fmaxf(mx, __shfl_xor(mx, 32));

    const float mold = mrow;
    const bool defer = __all(mx <= mold + DEFER_THR);   // T13: wave-uniform skip
    float mnew = mold;
    if (!defer) {
      mnew = fmaxf(mold, mx);
      const float corr = __builtin_amdgcn_exp2f(mold - mnew);
      mrow = mnew;
      lrow *= corr;
#pragma unroll
      for (int d = 0; d < 4; ++d) o[d] *= corr;         // lane-local: col(q)=fr
    }
#pragma unroll
    for (int c = 0; c < 4; ++c)
#pragma unroll
      for (int g = 0; g < 4; ++g)
        p[c][g] = __builtin_amdgcn_exp2f(p[c][g] - mnew);
    f32x4 s4 = (p[0] + p[1]) + (p[2] + p[3]);
    float rs = (s4[0] + s4[1]) + (s4[2] + s4[3]);
    rs += __shfl_xor(rs, 16);
    rs += __shfl_xor(rs, 32);
    lrow += rs;

    // P -> bf16 B-frags (P^T operand); key permutation makes this pack-only
    bf16x8 pa[2];
#pragma unroll
    for (int ks = 0; ks < 2; ++ks) {
      u32 w0 = pk2(p[2 * ks][0], p[2 * ks][1]);
      u32 w1 = pk2(p[2 * ks][2], p[2 * ks][3]);
      u32 w2 = pk2(p[2 * ks + 1][0], p[2 * ks + 1][1]);
      u32 w3 = pk2(p[2 * ks + 1][2], p[2 * ks + 1][3]);
      uint4 packed = {w0, w1, w2, w3};
      pa[ks] = __builtin_bit_cast(bf16x8, packed);
    }
    // O^T += V^T * P^T
    __builtin_amdgcn_s_setprio(1);
#pragma unroll
    for (int d = 0; d < 4; ++d) {
      o[d] = __builtin_amdgcn_mfma_f32_16x16x32_bf16(vf[d][0], pa[0], o[d], 0, 0, 0);
      o[d] = __builtin_amdgcn_mfma_f32_16x16x32_bf16(vf[d][1], pa[1], o[d], 0, 0, 0);
    }
    __builtin_amdgcn_s_setprio(0);
    __syncthreads();            // drains vmcnt (tile t+1 staged) + LDS reads done
  }

  // epilogue: lane-local 1/l, packed 8B stores. lane (fr,fg) holds
  // O^T[d = dblk*16 + fg*4 + g][q = fr] -> AO[b*2048 + q0 + fr][h*64 + d]
  {
    const float rinv = __builtin_amdgcn_rcpf(lrow);
    const size_t rowoff = (size_t)(b * 2048 + q0 + fr) * 1024 + h * 64;
#pragma unroll
    for (int d = 0; d < 4; ++d) {
      uint2 st;
      st.x = pk2(o[d][0] * rinv, o[d][1] * rinv);
      st.y = pk2(o[d][2] * rinv, o[d][3] * rinv);
      *(uint2*)(AO + rowoff + d * 16 + fg * 4) = st;
    }
  }
#undef STAGE
}

// ---------------- launch ----------------
extern "C" void kernel_launch(void* const* d_in, const int* in_sizes, int n_in,
                              void* d_out, int out_size, void* d_ws, size_t ws_size,
                              hipStream_t stream) {
  (void)in_sizes; (void)n_in; (void)out_size; (void)ws_size;
  const float* x     = (const float*)d_in[0];
  const float* w_in  = (const float*)d_in[1];
  const float* b_in  = (const float*)d_in[2];
  const float* w_out = (const float*)d_in[3];
  const float* b_out = (const float*)d_in[4];

  u16* xb    = (u16*)d_ws;                       // [4096,1024]
  u16* winb  = xb    + (size_t)4096 * 1024;      // [3072,1024]  (contiguous after xb)
  u16* woutb = winb  + (size_t)3072 * 1024;      // [1024,1024]  (contiguous after winb)
  u16* qb    = woutb + (size_t)1024 * 1024;      // [32,2048,64]
  u16* kb    = qb    + (size_t)4194304;          // [32,32,4096] tile images
  u16* vb    = kb    + (size_t)4194304;          // [32,32,4096] tile images
  u16* aob   = vb    + (size_t)4194304;          // [4096,1024]

  cvt_all_k<<<4096, 256, 0, stream>>>(x, w_in, w_out, xb);

  gemm_bt<0, 128><<<dim3(24, 32), 256, 0, stream>>>(xb, winb, b_in, qb, kb, vb, nullptr);
  attn_fwd<<<1024, 256, 0, stream>>>(qb, kb, vb, aob);
  gemm_bt<1, 64><<<dim3(8, 64), 256, 0, stream>>>(aob, woutb, b_out, nullptr, nullptr, nullptr,
                                                  (float*)d_out);
}

// Round 9
// 198.730 us; speedup vs baseline: 1.0770x; 1.0749x over previous
//
#include <hip/hip_runtime.h>

using u16 = unsigned short;
using u32 = unsigned int;

typedef __bf16 bf16x8 __attribute__((ext_vector_type(8)));
typedef __bf16 bf16x2 __attribute__((ext_vector_type(2)));
typedef float f32x4 __attribute__((ext_vector_type(4)));

__device__ __forceinline__ u16 f2b(float x) {
  u32 u = __builtin_bit_cast(u32, x);
  u += 0x7fffu + ((u >> 16) & 1u);   // RNE
  return (u16)(u >> 16);
}

// pack two f32 -> bf16x2 (low = first)
__device__ __forceinline__ u32 pk2(float lo, float hi) {
  bf16x2 t;
  t[0] = (__bf16)lo;
  t[1] = (__bf16)hi;
  return __builtin_bit_cast(u32, t);
}

__device__ __forceinline__ void gload16(const u16* g, u16* l) {
  __builtin_amdgcn_global_load_lds(
      (const __attribute__((address_space(1))) void*)g,
      (__attribute__((address_space(3))) void*)l, 16, 0, 0);
}

#define SCALE_Q 0.1803368801111204f   // 0.125 * log2(e): softmax in base-2
#define DEFER_THR 8.0f                // T13: P bounded by 2^8, fine in bf16/f32

// ---------------- fused fp32 -> bf16 convert (x, w_in, w_out -> contiguous ws) ----
__global__ __launch_bounds__(256) void cvt_all_k(
    const float* __restrict__ x, const float* __restrict__ w_in,
    const float* __restrict__ w_out, u16* __restrict__ dst) {
  const int i = blockIdx.x * 256 + threadIdx.x;
  const float* s;
  int j;
  if (i < 524288) { s = x; j = i; }
  else if (i < 917504) { s = w_in; j = i - 524288; }
  else { s = w_out; j = i - 917504; }
  float4 a = ((const float4*)s)[2 * j];
  float4 b = ((const float4*)s)[2 * j + 1];
  uint4 o;
  o.x = (u32)f2b(a.x) | ((u32)f2b(a.y) << 16);
  o.y = (u32)f2b(a.z) | ((u32)f2b(a.w) << 16);
  o.z = (u32)f2b(b.x) | ((u32)f2b(b.y) << 16);
  o.w = (u32)f2b(b.z) | ((u32)f2b(b.w) << 16);
  ((uint4*)dst)[i] = o;
}

// ---------------- bf16 GEMM, C = A * B^T (+bias) ----------------
// BK=64, G21 swizzle (pre-swizzled global source, linear gload_lds dest).
// MODE 0 (BM=128): N=3072. Epilogue writes q [bh][s][64] (pre-scaled), and K/V
//   in the attention LDS-image layout:
//   K: [bh][t][r][dd ^ ((r&7)<<3)], physical row r holds logical key L(r).
//   V: [bh][t][dd][sl ^ ((dd&7)<<3)] (transposed) — written as packed 8B uint2
//      (g=0..3 -> 4 consecutive sl within one XOR granule).
// MODE 1 (BM=64):  N=1024, write fp32 to outf.
template <int MODE, int BM>
__global__ __launch_bounds__(256) void gemm_bt(
    const u16* __restrict__ A, const u16* __restrict__ Bm,
    const float* __restrict__ bias,
    u16* __restrict__ q, u16* __restrict__ k, u16* __restrict__ v,
    float* __restrict__ outf) {
  constexpr int KD = 1024;
  constexpr int MR = BM / 32;              // row-frags per wave
  constexpr int CA = BM / 8;               // A staging chunks (1KB each)
  const int n0 = blockIdx.x * 128;
  const int m0 = blockIdx.y * BM;
  const int tid = threadIdx.x;
  const int wid = tid >> 6;
  const int lane = tid & 63;
  const int wr = wid >> 1, wc = wid & 1;   // 2x2 waves; wave tile (BM/2) x 64
  const int fr = lane & 15, fg = lane >> 4;
  const int srow = lane >> 3;              // row within 8-row chunk
  const int scol = ((lane & 7) ^ (srow & 7)) * 8;   // pre-swizzled source col

  __shared__ __align__(16) u16 As[BM * 64];
  __shared__ __align__(16) u16 Bs[128 * 64];

  f32x4 acc[MR][4] = {};

  for (int k0 = 0; k0 < KD; k0 += 64) {
#pragma unroll
    for (int i = 0; i < CA / 4; ++i) {
      const int chunk = wid * (CA / 4) + i;
      gload16(A + (size_t)(m0 + chunk * 8 + srow) * KD + k0 + scol, As + chunk * 512);
    }
#pragma unroll
    for (int i = 0; i < 4; ++i) {
      const int chunk = wid * 4 + i;
      gload16(Bm + (size_t)(n0 + chunk * 8 + srow) * KD + k0 + scol, Bs + chunk * 512);
    }
    __syncthreads();
#pragma unroll
    for (int ks = 0; ks < 2; ++ks) {
      bf16x8 af[MR], bfr[4];
#pragma unroll
      for (int r = 0; r < MR; ++r) {
        const int row = wr * (BM / 2) + r * 16 + fr;
        af[r] = *(const bf16x8*)(As + row * 64 + ((ks * 32 + fg * 8) ^ ((row & 7) * 8)));
      }
#pragma unroll
      for (int c = 0; c < 4; ++c) {
        const int row = wc * 64 + c * 16 + fr;
        bfr[c] = *(const bf16x8*)(Bs + row * 64 + ((ks * 32 + fg * 8) ^ ((row & 7) * 8)));
      }
#pragma unroll
      for (int r = 0; r < MR; ++r)
#pragma unroll
        for (int c = 0; c < 4; ++c)
          acc[r][c] = __builtin_amdgcn_mfma_f32_16x16x32_bf16(af[r], bfr[c], acc[r][c], 0, 0, 0);
    }
    __syncthreads();
  }

#pragma unroll
  for (int r = 0; r < MR; ++r) {
#pragma unroll
    for (int c = 0; c < 4; ++c) {
      const int gcol = n0 + wc * 64 + c * 16 + fr;
      const float bv = bias[gcol];
      if (MODE == 0) {
        const int which = gcol >> 10;            // 0=q 1=k 2=v
        const int dcol = gcol & 1023;
        const int hh = dcol >> 6, dd = dcol & 63;
        const int grow0 = m0 + wr * (BM / 2) + r * 16 + fg * 4;   // g=0 row
        const int bb = grow0 >> 11, ss0 = grow0 & 2047;
        const int bhk = (bb << 4) + hh;
        const int t = ss0 >> 6, sl0 = ss0 & 63;
        if (which == 2) {
          // packed 8B store: 4 consecutive sl in one XOR granule
          uint2 st;
          st.x = pk2(acc[r][c][0] + bv, acc[r][c][1] + bv);
          st.y = pk2(acc[r][c][2] + bv, acc[r][c][3] + bv);
          *(uint2*)(v + ((size_t)bhk * 32 + t) * 4096 + dd * 64 + (sl0 ^ ((dd & 7) << 3))) = st;
        } else if (which == 1) {
#pragma unroll
          for (int g = 0; g < 4; ++g) {
            const int sl = sl0 + g;
            const int r_ = (sl & 32) | (((sl >> 2) & 1) << 4) | (((sl >> 4) & 1) << 3) |
                           (((sl >> 3) & 1) << 2) | (sl & 3);
            k[((size_t)bhk * 32 + t) * 4096 + r_ * 64 + (dd ^ ((r_ & 7) << 3))] =
                f2b(acc[r][c][g] + bv);
          }
        } else {
#pragma unroll
          for (int g = 0; g < 4; ++g)
            q[((size_t)bhk * 2048 + ss0 + g) * 64 + dd] = f2b((acc[r][c][g] + bv) * SCALE_Q);
        }
      } else {
#pragma unroll
        for (int g = 0; g < 4; ++g) {
          const int grow = m0 + wr * (BM / 2) + r * 16 + fg * 4 + g;
          outf[(size_t)grow * 1024 + gcol] = acc[r][c][g] + bv;
        }
      }
    }
  }
}

// ---------------- flash attention fwd: counted-vmcnt 2-deep pipeline ----------------
// Q: [32 bh][2048][64] bf16 (pre-scaled). KG/VG: [32 bh][32 t][4096] tile images.
// AO: [4096][1024] bf16. 512 blocks x 4 waves x 32 q-rows (QBLK=128).
// Loop never drains vmcnt to 0 (T4): STAGE(t+2) issued right after the frag-read
// barrier; vmcnt(4) at loop head means tile t landed while t+1 stays in flight.
// Row-sum via mfma(ones, pa) -> column sums (moves sum off the VALU stream).
__global__ __launch_bounds__(256) void attn_fwd(
    const u16* __restrict__ Q, const u16* __restrict__ KG,
    const u16* __restrict__ VG, u16* __restrict__ AO) {
  const int wg = blockIdx.x;                     // 512
  const int newid = (wg & 7) * 64 + (wg >> 3);   // XCD swizzle (bijective: 512%8==0)
  const int bh = newid >> 4;
  const int qt = newid & 15;
  const int b = bh >> 4, h = bh & 15;

  const int tid = threadIdx.x, wid = tid >> 6, lane = tid & 63;
  const int fr = lane & 15, fg = lane >> 4;
  const int q0 = qt * 128 + wid * 32;

  __shared__ __align__(16) u16 Ks[2][4096];      // 8KB per buffer
  __shared__ __align__(16) u16 Vs[2][4096];

  const size_t qbase = (size_t)bh * (2048 * 64);
  bf16x8 qf[2][2];
#pragma unroll
  for (int rf = 0; rf < 2; ++rf)
#pragma unroll
    for (int ks = 0; ks < 2; ++ks)
      qf[rf][ks] = *(const bf16x8*)(Q + qbase + (size_t)(q0 + rf * 16 + fr) * 64 + ks * 32 + fg * 8);

  bf16x8 onef;
#pragma unroll
  for (int i = 0; i < 8; ++i) onef[i] = (__bf16)1.0f;

  f32x4 o[2][4] = {};                       // O^T: col=q=fr, row=d=4*fg+g
  f32x4 l4[2] = {};                         // colsum accumulator (all rows equal)
  float mrow[2] = {-3.0e38f, -3.0e38f};

  const u16* kg = KG + (size_t)bh * 131072 + tid * 8;   // per-thread 16B slice
  const u16* vg = VG + (size_t)bh * 131072 + tid * 8;

#define STAGE(t, bufi) do {                                        \
    const u16* ksrc = kg + (t) * 4096;                             \
    const u16* vsrc = vg + (t) * 4096;                             \
    u16* kdst = (u16*)Ks[bufi] + wid * 512;                        \
    u16* vdst = (u16*)Vs[bufi] + wid * 512;                        \
    gload16(ksrc, kdst); gload16(ksrc + 2048, kdst + 2048);        \
    gload16(vsrc, vdst); gload16(vsrc + 2048, vdst + 2048);        \
  } while (0)

  STAGE(0, 0);
  STAGE(1, 1);                              // 8 loads in flight

  for (int t = 0; t < 32; ++t) {
    const int cur = t & 1;
    // tile t landed; tile t+1's 4 loads stay in flight (counted wait, no drain)
    asm volatile("s_waitcnt vmcnt(4)" ::: "memory");
    __builtin_amdgcn_s_barrier();

    const u16* kb = (const u16*)Ks[cur];
    const u16* vb = (const u16*)Vs[cur];
    bf16x8 kf[4][2], vf[4][2];
#pragma unroll
    for (int c = 0; c < 4; ++c)
#pragma unroll
      for (int ks = 0; ks < 2; ++ks)
        kf[c][ks] = *(const bf16x8*)(kb + (c * 16 + fr) * 64 + ((ks * 32 + fg * 8) ^ ((fr & 7) * 8)));
#pragma unroll
    for (int d = 0; d < 4; ++d)
#pragma unroll
      for (int ks = 0; ks < 2; ++ks)
        vf[d][ks] = *(const bf16x8*)(vb + (d * 16 + fr) * 64 + ((ks * 32 + fg * 8) ^ ((fr & 7) * 8)));
    // all waves' frag reads retired -> buf[cur] safe to overwrite
    asm volatile("s_waitcnt lgkmcnt(0)" ::: "memory");
    __builtin_amdgcn_sched_barrier(0);
    __builtin_amdgcn_s_barrier();
    STAGE((t + 2) & 31, cur);               // wraps at tail: harmless re-read

#pragma unroll
    for (int rf = 0; rf < 2; ++rf) {
      f32x4 p[4];
      __builtin_amdgcn_s_setprio(1);
#pragma unroll
      for (int c = 0; c < 4; ++c) {
        f32x4 z = {};
        z = __builtin_amdgcn_mfma_f32_16x16x32_bf16(kf[c][0], qf[rf][0], z, 0, 0, 0);
        z = __builtin_amdgcn_mfma_f32_16x16x32_bf16(kf[c][1], qf[rf][1], z, 0, 0, 0);
        p[c] = z;
      }
      __builtin_amdgcn_s_setprio(0);
      // row max: vector tree + horizontal + fg-group reduce
      f32x4 m01 = __builtin_elementwise_max(p[0], p[1]);
      f32x4 m23 = __builtin_elementwise_max(p[2], p[3]);
      f32x4 m4 = __builtin_elementwise_max(m01, m23);
      float mx = fmaxf(fmaxf(m4[0], m4[1]), fmaxf(m4[2], m4[3]));
      mx = fmaxf(mx, __shfl_xor(mx, 16));
      mx = fmaxf(mx, __shfl_xor(mx, 32));

      const float mold = mrow[rf];
      const bool defer = __all(mx <= mold + DEFER_THR);   // T13: wave-uniform skip
      float mnew = mold;
      if (!defer) {
        mnew = fmaxf(mold, mx);
        const float corr = __builtin_amdgcn_exp2f(mold - mnew);
        mrow[rf] = mnew;
        l4[rf] *= corr;
#pragma unroll
        for (int d = 0; d < 4; ++d) o[rf][d] *= corr;     // lane-local: col(q)=fr
      }
#pragma unroll
      for (int c = 0; c < 4; ++c)
#pragma unroll
        for (int g = 0; g < 4; ++g)
          p[c][g] = __builtin_amdgcn_exp2f(p[c][g] - mnew);

      // P -> bf16 B-frags (P^T operand); key permutation makes this pack-only
      bf16x8 pa[2];
#pragma unroll
      for (int ks = 0; ks < 2; ++ks) {
        u32 w0 = pk2(p[2 * ks][0], p[2 * ks][1]);
        u32 w1 = pk2(p[2 * ks][2], p[2 * ks][3]);
        u32 w2 = pk2(p[2 * ks + 1][0], p[2 * ks + 1][1]);
        u32 w3 = pk2(p[2 * ks + 1][2], p[2 * ks + 1][3]);
        uint4 packed = {w0, w1, w2, w3};
        pa[ks] = __builtin_bit_cast(bf16x8, packed);
      }
      // O^T += V^T P^T; l4 += Ones·P^T (column sums -> every lane has row-sum)
      __builtin_amdgcn_s_setprio(1);
      l4[rf] = __builtin_amdgcn_mfma_f32_16x16x32_bf16(onef, pa[0], l4[rf], 0, 0, 0);
      l4[rf] = __builtin_amdgcn_mfma_f32_16x16x32_bf16(onef, pa[1], l4[rf], 0, 0, 0);
#pragma unroll
      for (int d = 0; d < 4; ++d) {
        o[rf][d] = __builtin_amdgcn_mfma_f32_16x16x32_bf16(vf[d][0], pa[0], o[rf][d], 0, 0, 0);
        o[rf][d] = __builtin_amdgcn_mfma_f32_16x16x32_bf16(vf[d][1], pa[1], o[rf][d], 0, 0, 0);
      }
      __builtin_amdgcn_s_setprio(0);
    }
  }
  asm volatile("s_waitcnt vmcnt(0)" ::: "memory");   // drain dummy tail stages

  // epilogue: lane-local 1/l, packed 8B stores
#pragma unroll
  for (int rf = 0; rf < 2; ++rf) {
    const float rinv = __builtin_amdgcn_rcpf(l4[rf][0]);
    const size_t rowoff = (size_t)(b * 2048 + q0 + rf * 16 + fr) * 1024 + h * 64;
#pragma unroll
    for (int d = 0; d < 4; ++d) {
      uint2 st;
      st.x = pk2(o[rf][d][0] * rinv, o[rf][d][1] * rinv);
      st.y = pk2(o[rf][d][2] * rinv, o[rf][d][3] * rinv);
      *(uint2*)(AO + rowoff + d * 16 + fg * 4) = st;
    }
  }
#undef STAGE
}

// ---------------- launch ----------------
extern "C" void kernel_launch(void* const* d_in, const int* in_sizes, int n_in,
                              void* d_out, int out_size, void* d_ws, size_t ws_size,
                              hipStream_t stream) {
  (void)in_sizes; (void)n_in; (void)out_size; (void)ws_size;
  const float* x     = (const float*)d_in[0];
  const float* w_in  = (const float*)d_in[1];
  const float* b_in  = (const float*)d_in[2];
  const float* w_out = (const float*)d_in[3];
  const float* b_out = (const float*)d_in[4];

  u16* xb    = (u16*)d_ws;                       // [4096,1024]
  u16* winb  = xb    + (size_t)4096 * 1024;      // [3072,1024]
  u16* woutb = winb  + (size_t)3072 * 1024;      // [1024,1024]
  u16* qb    = woutb + (size_t)1024 * 1024;      // [32,2048,64]
  u16* kb    = qb    + (size_t)4194304;          // [32,32,4096] tile images
  u16* vb    = kb    + (size_t)4194304;          // [32,32,4096] tile images
  u16* aob   = vb    + (size_t)4194304;          // [4096,1024]

  cvt_all_k<<<4096, 256, 0, stream>>>(x, w_in, w_out, xb);

  gemm_bt<0, 128><<<dim3(24, 32), 256, 0, stream>>>(xb, winb, b_in, qb, kb, vb, nullptr);
  attn_fwd<<<512, 256, 0, stream>>>(qb, kb, vb, aob);
  gemm_bt<1, 64><<<dim3(8, 64), 256, 0, stream>>>(aob, woutb, b_out, nullptr, nullptr, nullptr,
                                                  (float*)d_out);
}